// Round 1
// baseline (4914.946 us; speedup 1.0000x reference)
//
#include <hip/hip_runtime.h>
#include <stdint.h>

// ModeloNeuralVasicek: 2520-step Euler-Maruyama neural SDE, B=64 x Q=256 paths.
// One block per batch element (fully independent). Bit-exact JAX threefry RNG.
// PARTITIONABLE=1 assumes jax_threefry_partitionable default True (JAX >= 0.5).
#ifndef PARTITIONABLE
#define PARTITIONABLE 1
#endif

#define NSTEPS 2520
#define NB 64
#define NT 256
#define NQ 256
#define NMAT 7

__device__ __forceinline__ uint32_t rotl32(uint32_t v, int n) {
  return (v << n) | (v >> (32 - n));
}

// Threefry-2x32, 20 rounds — matches jax._src.prng.threefry2x32 exactly.
__device__ __forceinline__ void tf2x32(uint32_t k0, uint32_t k1,
                                       uint32_t x0, uint32_t x1,
                                       uint32_t& o0, uint32_t& o1) {
  const uint32_t k2 = k0 ^ k1 ^ 0x1BD11BDAu;
  x0 += k0; x1 += k1;
#define R4(a,b,c,d) \
  x0 += x1; x1 = rotl32(x1,(a)); x1 ^= x0; \
  x0 += x1; x1 = rotl32(x1,(b)); x1 ^= x0; \
  x0 += x1; x1 = rotl32(x1,(c)); x1 ^= x0; \
  x0 += x1; x1 = rotl32(x1,(d)); x1 ^= x0;
  R4(13,15,26,6)  x0 += k1; x1 += k2 + 1u;
  R4(17,29,16,24) x0 += k2; x1 += k0 + 2u;
  R4(13,15,26,6)  x0 += k0; x1 += k1 + 3u;
  R4(17,29,16,24) x0 += k1; x1 += k2 + 4u;
  R4(13,15,26,6)  x0 += k2; x1 += k0 + 5u;
#undef R4
  o0 = x0; o1 = x1;
}

// Eigen/XLA generic_fast_tanh_float (what XLA emits for f32 tanh).
__device__ __forceinline__ float eigen_tanh(float a_x) {
  float x = fminf(fmaxf(a_x, -7.90531110763549805f), 7.90531110763549805f);
  float x2 = x * x;
  float p = __builtin_fmaf(x2, -2.76076847742355e-16f, 2.00018790482477e-13f);
  p = __builtin_fmaf(x2, p, -8.60467152213735e-11f);
  p = __builtin_fmaf(x2, p, 5.12229709037114e-08f);
  p = __builtin_fmaf(x2, p, 1.48572235717979e-05f);
  p = __builtin_fmaf(x2, p, 6.37261928875436e-04f);
  p = __builtin_fmaf(x2, p, 4.89352455891786e-03f);
  p = x * p;
  float q = __builtin_fmaf(x2, 1.19825839466702e-06f, 1.18534705686654e-04f);
  q = __builtin_fmaf(x2, q, 2.26843463243900e-03f);
  q = __builtin_fmaf(x2, q, 4.89352518554385e-03f);
  float rr = p / q;
  return (fabsf(a_x) < 0.0004f) ? a_x : rr;
}

// Eigen/XLA generic_fast_erf_float (chlo.erf f32 lowering).
__device__ __forceinline__ float eigen_erf(float a_x) {
  float x = fminf(fmaxf(a_x, -4.0f), 4.0f);
  float x2 = x * x;
  float p = __builtin_fmaf(x2, -2.72614225801306e-10f, 2.77068142495902e-08f);
  p = __builtin_fmaf(x2, p, -2.10102402082508e-06f);
  p = __builtin_fmaf(x2, p, -5.69250639462346e-05f);
  p = __builtin_fmaf(x2, p, -7.34990630326855e-04f);
  p = __builtin_fmaf(x2, p, -2.95459980854025e-03f);
  p = __builtin_fmaf(x2, p, -1.60960333262415e-02f);
  p = x * p;
  float q = __builtin_fmaf(x2, -1.45660718464996e-05f, -2.13374055278905e-04f);
  q = __builtin_fmaf(x2, q, -1.68282697438203e-03f);
  q = __builtin_fmaf(x2, q, -7.37332916720468e-03f);
  q = __builtin_fmaf(x2, q, -1.42647390514189e-02f);
  return p / q;
}

// jax.nn.gelu(approximate=False): x * (erf(x/sqrt(2)) + 1) / 2
__device__ __forceinline__ float gelu_exact(float x) {
  float t = x / 1.41421356237309515f;
  float e = eigen_erf(t);
  return x * (e + 1.0f) * 0.5f;
}

// jax.nn.softplus = logaddexp(x, 0) = max(x,0) + log1p(exp(-|x|))
__device__ __forceinline__ float softplus_jax(float x) {
  return fmaxf(x, 0.0f) + log1pf(expf(-fabsf(x)));
}

// XLA chlo.erf_inv f32 lowering (Giles single-precision polynomial).
__device__ __forceinline__ float erfinv_xla(float x) {
  float w = -logf((1.0f - x) * (1.0f + x));
  float p;
  if (w < 5.0f) {
    w = w - 2.5f;
    p = 2.81022636e-08f;
    p = __builtin_fmaf(p, w, 3.43273939e-07f);
    p = __builtin_fmaf(p, w, -3.5233877e-06f);
    p = __builtin_fmaf(p, w, -4.39150654e-06f);
    p = __builtin_fmaf(p, w, 0.00021858087f);
    p = __builtin_fmaf(p, w, -0.00125372503f);
    p = __builtin_fmaf(p, w, -0.00417768164f);
    p = __builtin_fmaf(p, w, 0.246640727f);
    p = __builtin_fmaf(p, w, 1.50140941f);
  } else {
    w = sqrtf(w) - 3.0f;
    p = -0.000200214257f;
    p = __builtin_fmaf(p, w, 0.000100950558f);
    p = __builtin_fmaf(p, w, 0.00134934322f);
    p = __builtin_fmaf(p, w, -0.00367342844f);
    p = __builtin_fmaf(p, w, 0.00573950773f);
    p = __builtin_fmaf(p, w, -0.0076224613f);
    p = __builtin_fmaf(p, w, 0.00943887047f);
    p = __builtin_fmaf(p, w, 1.00167406f);
    p = __builtin_fmaf(p, w, 2.83297682f);
  }
  return p * x;
}

// JAX uniform(-(1-2^-24), 1) -> sqrt(2)*erfinv(u), bit-faithful.
__device__ __forceinline__ float bits_to_normal(uint32_t bits) {
  const float MINVAL = -0.999999940395355224609375f;  // nextafter(-1,0) in f32
  uint32_t fb = (bits >> 9) | 0x3F800000u;
  float f01 = __uint_as_float(fb) - 1.0f;     // [0, 1-2^-24]
  float u = f01 * 2.0f + MINVAL;              // *2 exact; add RN (matches XLA)
  u = fmaxf(u, MINVAL);
  return 1.41421356237309515f * erfinv_xla(u);
}

__global__ __launch_bounds__(256, 1)
void ModeloNeuralVasicek_88158498717914_kernel(
    const float* __restrict__ X, const float* __restrict__ r_ult,
    const float* __restrict__ mats,
    const float* __restrict__ Wp, const float* __restrict__ bp,
    const float* __restrict__ ln_g, const float* __restrict__ ln_b,
    const float* __restrict__ muW1, const float* __restrict__ mub1,
    const float* __restrict__ muW2, const float* __restrict__ mub2,
    const float* __restrict__ muW3, const float* __restrict__ mub3,
    const float* __restrict__ siW1, const float* __restrict__ sib1,
    const float* __restrict__ siW2, const float* __restrict__ sib2,
    const float* __restrict__ siW3, const float* __restrict__ sib3,
    float* __restrict__ out) {
  const int b = blockIdx.x;
  const int tid = threadIdx.x;
  const int lane = tid & 63;
  const int wv = tid >> 6;

  __shared__ float part[256];
  __shared__ float mbuf[64];
  __shared__ float ctx_lds[192];
  __shared__ __align__(16) float h1_lds[256];
  __shared__ float psum[4];
  __shared__ float msum[4];
  __shared__ uint32_t kA[NSTEPS];
  __shared__ uint32_t kB[NSTEPS];

  // ---- per-step keys: jax.random.split(key(1), 2520) ----
  for (int i = tid; i < NSTEPS; i += 256) {
#if PARTITIONABLE
    uint32_t o0, o1;
    tf2x32(0u, 1u, 0u, (uint32_t)i, o0, o1);   // fold-like split: both outputs
    kA[i] = o0; kB[i] = o1;
#else
    uint32_t o0, o1, d0, d1;
    if (i < 1260) {
      tf2x32(0u, 1u, (uint32_t)(2 * i),     (uint32_t)(2 * i + 2520),     o0, d0);
      tf2x32(0u, 1u, (uint32_t)(2 * i + 1), (uint32_t)(2 * i + 1 + 2520), o1, d1);
    } else {
      tf2x32(0u, 1u, (uint32_t)(2 * i - 2520),     (uint32_t)(2 * i),     d0, o0);
      tf2x32(0u, 1u, (uint32_t)(2 * i + 1 - 2520), (uint32_t)(2 * i + 1), d1, o1);
    }
    kA[i] = o0; kB[i] = o1;
#endif
  }

  // ---- context aggregator: H = LN(tanh(X@Wp+bp)); ctx = [mean_t, std_t(ddof=1), last] ----
  float h[64];
  {
    float x0 = X[(b * NT + tid) * 2 + 0];
    float x1 = X[(b * NT + tid) * 2 + 1];
    float s = 0.f;
#pragma unroll
    for (int c = 0; c < 64; ++c) {
      float pre = __builtin_fmaf(x1, Wp[64 + c], x0 * Wp[c]) + bp[c];
      h[c] = eigen_tanh(pre);
      s += h[c];
    }
    float m = s * 0.015625f;
    float vs = 0.f;
#pragma unroll
    for (int c = 0; c < 64; ++c) { float d = h[c] - m; vs = __builtin_fmaf(d, d, vs); }
    float den = sqrtf(vs * 0.015625f + 1e-5f);
#pragma unroll
    for (int c = 0; c < 64; ++c)
      h[c] = ((h[c] - m) / den) * ln_g[c] + ln_b[c];
  }
  // channel means over T (rows live in registers; butterfly within wave, 4 partials)
#pragma unroll
  for (int c = 0; c < 64; ++c) {
    float v = h[c];
    v += __shfl_xor(v, 32, 64); v += __shfl_xor(v, 16, 64);
    v += __shfl_xor(v, 8, 64);  v += __shfl_xor(v, 4, 64);
    v += __shfl_xor(v, 2, 64);  v += __shfl_xor(v, 1, 64);
    if (lane == 0) part[wv * 64 + c] = v;
  }
  __syncthreads();
  if (tid < 64) {
    float m = ((part[tid] + part[64 + tid]) + (part[128 + tid] + part[192 + tid])) * (1.0f / 256.0f);
    mbuf[tid] = m;
    ctx_lds[tid] = m;
  }
  __syncthreads();
#pragma unroll
  for (int c = 0; c < 64; ++c) {
    float d = h[c] - mbuf[c];
    float v = d * d;
    v += __shfl_xor(v, 32, 64); v += __shfl_xor(v, 16, 64);
    v += __shfl_xor(v, 8, 64);  v += __shfl_xor(v, 4, 64);
    v += __shfl_xor(v, 2, 64);  v += __shfl_xor(v, 1, 64);
    if (lane == 0) part[wv * 64 + c] = v;
  }
  if (tid == 255) {
#pragma unroll
    for (int c = 0; c < 64; ++c) ctx_lds[128 + c] = h[c];  // H[:, -1, :]
  }
  __syncthreads();
  if (tid < 64) {
    float vs = (part[tid] + part[64 + tid]) + (part[128 + tid] + part[192 + tid]);
    ctx_lds[64 + tid] = sqrtf(vs / 255.0f);  // ddof=1
  }
  __syncthreads();

  // ---- per-thread MLP constants: thread 0..127 -> mu output j, 128..255 -> si output j ----
  const bool is_mu = tid < 128;
  const int j = is_mu ? tid : tid - 128;
  const float* W1 = is_mu ? muW1 : siW1;
  const float* W2 = is_mu ? muW2 : siW2;
  float c1 = (is_mu ? mub1 : sib1)[j];  // fold bias + constant ctx part of layer 1
  for (int c = 0; c < 192; ++c)
    c1 = __builtin_fmaf(ctx_lds[c], W1[(2 + c) * 128 + j], c1);
  const float w10 = W1[j];         // W1 row 0 (r_mean)
  const float w11 = W1[128 + j];   // W1 row 1 (t)
  const float b2s = (is_mu ? mub2 : sib2)[j];
  const float w3s = (is_mu ? muW3 : siW3)[j];
  const float b3mu = mub3[0];
  const float b3si = sib3[0];

  float w2[128];  // W2 column j, pinned in VGPRs (launch_bounds(256,1) -> 512 VGPR budget)
#pragma unroll
  for (int k = 0; k < 128; ++k) w2[k] = W2[k * 128 + j];

  // ---- path state: thread q owns path q of batch b ----
  float r = r_ult[b];
  float area = 0.f;
  const uint32_t cnt = (uint32_t)(b * NQ + tid);  // linear index into (B,Q)

  const float DTF = (float)(1.0 / 252.0);
  const float SQDT = 0.06299407883487120442f;  // f32(sqrt(1/252))
  const float TSTEP = 1.0f / 2519.0f;          // linspace(0,1,2520) step

#pragma unroll 1
  for (int s = 0; s < NSTEPS; ++s) {
    // r.mean over 256 paths
    float v = r;
    v += __shfl_xor(v, 32, 64); v += __shfl_xor(v, 16, 64);
    v += __shfl_xor(v, 8, 64);  v += __shfl_xor(v, 4, 64);
    v += __shfl_xor(v, 2, 64);  v += __shfl_xor(v, 1, 64);
    if (lane == 0) psum[wv] = v;
    __syncthreads();  // barrier 1
    const float r_mean = ((psum[0] + psum[1]) + (psum[2] + psum[3])) * (1.0f / 256.0f);
    const float tval = TSTEP * (float)s;

    // dW: independent of MLP chain — scheduled to overlap
    uint32_t q0, q1;
#if PARTITIONABLE
    tf2x32(kA[s], kB[s], 0u, cnt, q0, q1);
    const uint32_t bits = q0 ^ q1;
#else
    const uint32_t c0 = (cnt < 8192u) ? cnt : (cnt - 8192u);
    tf2x32(kA[s], kB[s], c0, c0 + 8192u, q0, q1);
    const uint32_t bits = (cnt < 8192u) ? q0 : q1;
#endif
    const float dW = bits_to_normal(bits) * SQDT;

    // layer 1 (ctx part precomputed): 2 FMAs + gelu
    float pre = __builtin_fmaf(tval, w11, __builtin_fmaf(r_mean, w10, c1));
    h1_lds[tid] = gelu_exact(pre);
    __syncthreads();  // barrier 2

    // layer 2: 128-MAC dot; h1 via LDS float4 broadcasts, W2 column in registers
    const float4* hv = (const float4*)(h1_lds + (is_mu ? 0 : 128));
    float a0 = 0.f, a1 = 0.f, a2 = 0.f, a3 = 0.f;
#pragma unroll
    for (int k = 0; k < 32; ++k) {
      float4 h4 = hv[k];
      a0 = __builtin_fmaf(h4.x, w2[4 * k + 0], a0);
      a1 = __builtin_fmaf(h4.y, w2[4 * k + 1], a1);
      a2 = __builtin_fmaf(h4.z, w2[4 * k + 2], a2);
      a3 = __builtin_fmaf(h4.w, w2[4 * k + 3], a3);
    }
    float h2 = ((a0 + a1) + (a2 + a3)) + b2s;
    // layer 3: dot over 128 outputs = 2-wave reduction
    float p = gelu_exact(h2) * w3s;
    p += __shfl_xor(p, 32, 64); p += __shfl_xor(p, 16, 64);
    p += __shfl_xor(p, 8, 64);  p += __shfl_xor(p, 4, 64);
    p += __shfl_xor(p, 2, 64);  p += __shfl_xor(p, 1, 64);
    if (lane == 0) msum[wv] = p;
    __syncthreads();  // barrier 3
    const float mu = (msum[0] + msum[1]) + b3mu;
    const float si_raw = (msum[2] + msum[3]) + b3si;
    const float si = softplus_jax(si_raw) + 1e-5f;

    // r = (r + mu*DT) + si*dW ; area += r*DT — non-fused to mirror XLA elementwise
    r = __fadd_rn(__fadd_rn(r, __fmul_rn(mu, DTF)), __fmul_rn(si, dW));
    area = __fadd_rn(area, __fmul_rn(r, DTF));
  }

  // area.mean(1) then output: (am * (m/maxT)) / m for each maturity
  float v2 = area;
  v2 += __shfl_xor(v2, 32, 64); v2 += __shfl_xor(v2, 16, 64);
  v2 += __shfl_xor(v2, 8, 64);  v2 += __shfl_xor(v2, 4, 64);
  v2 += __shfl_xor(v2, 2, 64);  v2 += __shfl_xor(v2, 1, 64);
  if (lane == 0) psum[wv] = v2;
  __syncthreads();
  if (tid < NMAT) {
    const float am = ((psum[0] + psum[1]) + (psum[2] + psum[3])) * (1.0f / 256.0f);
    float mx = mats[0];
#pragma unroll
    for (int i = 1; i < NMAT; ++i) mx = fmaxf(mx, mats[i]);
    const float m = mats[tid];
    const float frac = m / (mx + 1e-12f);
    out[b * NMAT + tid] = (am * frac) / (m + 1e-12f);
  }
}

extern "C" void kernel_launch(void* const* d_in, const int* in_sizes, int n_in,
                              void* d_out, int out_size, void* d_ws, size_t ws_size,
                              hipStream_t stream) {
  (void)in_sizes; (void)n_in; (void)d_ws; (void)ws_size; (void)out_size;
  const float* X      = (const float*)d_in[0];
  const float* r_ult  = (const float*)d_in[1];
  const float* mats   = (const float*)d_in[2];
  const float* Wp     = (const float*)d_in[3];
  const float* bp     = (const float*)d_in[4];
  const float* ln_g   = (const float*)d_in[5];
  const float* ln_b   = (const float*)d_in[6];
  const float* muW1   = (const float*)d_in[7];
  const float* mub1   = (const float*)d_in[8];
  const float* muW2   = (const float*)d_in[9];
  const float* mub2   = (const float*)d_in[10];
  const float* muW3   = (const float*)d_in[11];
  const float* mub3   = (const float*)d_in[12];
  const float* siW1   = (const float*)d_in[13];
  const float* sib1   = (const float*)d_in[14];
  const float* siW2   = (const float*)d_in[15];
  const float* sib2   = (const float*)d_in[16];
  const float* siW3   = (const float*)d_in[17];
  const float* sib3   = (const float*)d_in[18];
  hipLaunchKernelGGL(ModeloNeuralVasicek_88158498717914_kernel,
                     dim3(NB), dim3(256), 0, stream,
                     X, r_ult, mats, Wp, bp, ln_g, ln_b,
                     muW1, mub1, muW2, mub2, muW3, mub3,
                     siW1, sib1, siW2, sib2, siW3, sib3,
                     (float*)d_out);
}

// Round 2
// 4537.902 us; speedup vs baseline: 1.0831x; 1.0831x over previous
//
#include <hip/hip_runtime.h>
#include <stdint.h>

// ModeloNeuralVasicek: 2520-step Euler-Maruyama neural SDE, B=64 x Q=256 paths.
// One block per batch element (fully independent). Bit-exact JAX threefry RNG.
// Round 2: W2 columns in eight named 512-bit ext-vectors (register-resident;
// the float w2[128] alloca was NOT promoted -> scratch reads dominated, VGPR=92).
#ifndef PARTITIONABLE
#define PARTITIONABLE 1
#endif

#define NSTEPS 2520
#define NB 64
#define NT 256
#define NQ 256
#define NMAT 7

typedef float f16v __attribute__((ext_vector_type(16)));
typedef float f4v  __attribute__((ext_vector_type(4)));

__device__ __forceinline__ uint32_t rotl32(uint32_t v, int n) {
  return (v << n) | (v >> (32 - n));
}

// Threefry-2x32, 20 rounds — matches jax._src.prng.threefry2x32 exactly.
__device__ __forceinline__ void tf2x32(uint32_t k0, uint32_t k1,
                                       uint32_t x0, uint32_t x1,
                                       uint32_t& o0, uint32_t& o1) {
  const uint32_t k2 = k0 ^ k1 ^ 0x1BD11BDAu;
  x0 += k0; x1 += k1;
#define R4(a,b,c,d) \
  x0 += x1; x1 = rotl32(x1,(a)); x1 ^= x0; \
  x0 += x1; x1 = rotl32(x1,(b)); x1 ^= x0; \
  x0 += x1; x1 = rotl32(x1,(c)); x1 ^= x0; \
  x0 += x1; x1 = rotl32(x1,(d)); x1 ^= x0;
  R4(13,15,26,6)  x0 += k1; x1 += k2 + 1u;
  R4(17,29,16,24) x0 += k2; x1 += k0 + 2u;
  R4(13,15,26,6)  x0 += k0; x1 += k1 + 3u;
  R4(17,29,16,24) x0 += k1; x1 += k2 + 4u;
  R4(13,15,26,6)  x0 += k2; x1 += k0 + 5u;
#undef R4
  o0 = x0; o1 = x1;
}

// Eigen/XLA generic_fast_tanh_float (what XLA emits for f32 tanh).
__device__ __forceinline__ float eigen_tanh(float a_x) {
  float x = fminf(fmaxf(a_x, -7.90531110763549805f), 7.90531110763549805f);
  float x2 = x * x;
  float p = __builtin_fmaf(x2, -2.76076847742355e-16f, 2.00018790482477e-13f);
  p = __builtin_fmaf(x2, p, -8.60467152213735e-11f);
  p = __builtin_fmaf(x2, p, 5.12229709037114e-08f);
  p = __builtin_fmaf(x2, p, 1.48572235717979e-05f);
  p = __builtin_fmaf(x2, p, 6.37261928875436e-04f);
  p = __builtin_fmaf(x2, p, 4.89352455891786e-03f);
  p = x * p;
  float q = __builtin_fmaf(x2, 1.19825839466702e-06f, 1.18534705686654e-04f);
  q = __builtin_fmaf(x2, q, 2.26843463243900e-03f);
  q = __builtin_fmaf(x2, q, 4.89352518554385e-03f);
  float rr = p / q;
  return (fabsf(a_x) < 0.0004f) ? a_x : rr;
}

// Eigen/XLA generic_fast_erf_float (chlo.erf f32 lowering).
__device__ __forceinline__ float eigen_erf(float a_x) {
  float x = fminf(fmaxf(a_x, -4.0f), 4.0f);
  float x2 = x * x;
  float p = __builtin_fmaf(x2, -2.72614225801306e-10f, 2.77068142495902e-08f);
  p = __builtin_fmaf(x2, p, -2.10102402082508e-06f);
  p = __builtin_fmaf(x2, p, -5.69250639462346e-05f);
  p = __builtin_fmaf(x2, p, -7.34990630326855e-04f);
  p = __builtin_fmaf(x2, p, -2.95459980854025e-03f);
  p = __builtin_fmaf(x2, p, -1.60960333262415e-02f);
  p = x * p;
  float q = __builtin_fmaf(x2, -1.45660718464996e-05f, -2.13374055278905e-04f);
  q = __builtin_fmaf(x2, q, -1.68282697438203e-03f);
  q = __builtin_fmaf(x2, q, -7.37332916720468e-03f);
  q = __builtin_fmaf(x2, q, -1.42647390514189e-02f);
  return p / q;
}

// jax.nn.gelu(approximate=False): x * (erf(x/sqrt(2)) + 1) / 2
__device__ __forceinline__ float gelu_exact(float x) {
  float t = x / 1.41421356237309515f;
  float e = eigen_erf(t);
  return x * (e + 1.0f) * 0.5f;
}

// jax.nn.softplus = logaddexp(x, 0) = max(x,0) + log1p(exp(-|x|))
__device__ __forceinline__ float softplus_jax(float x) {
  return fmaxf(x, 0.0f) + log1pf(expf(-fabsf(x)));
}

// XLA chlo.erf_inv f32 lowering (Giles single-precision polynomial).
__device__ __forceinline__ float erfinv_xla(float x) {
  float w = -logf((1.0f - x) * (1.0f + x));
  float p;
  if (w < 5.0f) {
    w = w - 2.5f;
    p = 2.81022636e-08f;
    p = __builtin_fmaf(p, w, 3.43273939e-07f);
    p = __builtin_fmaf(p, w, -3.5233877e-06f);
    p = __builtin_fmaf(p, w, -4.39150654e-06f);
    p = __builtin_fmaf(p, w, 0.00021858087f);
    p = __builtin_fmaf(p, w, -0.00125372503f);
    p = __builtin_fmaf(p, w, -0.00417768164f);
    p = __builtin_fmaf(p, w, 0.246640727f);
    p = __builtin_fmaf(p, w, 1.50140941f);
  } else {
    w = sqrtf(w) - 3.0f;
    p = -0.000200214257f;
    p = __builtin_fmaf(p, w, 0.000100950558f);
    p = __builtin_fmaf(p, w, 0.00134934322f);
    p = __builtin_fmaf(p, w, -0.00367342844f);
    p = __builtin_fmaf(p, w, 0.00573950773f);
    p = __builtin_fmaf(p, w, -0.0076224613f);
    p = __builtin_fmaf(p, w, 0.00943887047f);
    p = __builtin_fmaf(p, w, 1.00167406f);
    p = __builtin_fmaf(p, w, 2.83297682f);
  }
  return p * x;
}

// JAX uniform(-(1-2^-24), 1) -> sqrt(2)*erfinv(u), bit-faithful.
__device__ __forceinline__ float bits_to_normal(uint32_t bits) {
  const float MINVAL = -0.999999940395355224609375f;  // nextafter(-1,0) in f32
  uint32_t fb = (bits >> 9) | 0x3F800000u;
  float f01 = __uint_as_float(fb) - 1.0f;     // [0, 1-2^-24]
  float u = f01 * 2.0f + MINVAL;              // *2 exact; add RN (matches XLA)
  u = fmaxf(u, MINVAL);
  return 1.41421356237309515f * erfinv_xla(u);
}

__global__ __launch_bounds__(256, 1)
void ModeloNeuralVasicek_88158498717914_kernel(
    const float* __restrict__ X, const float* __restrict__ r_ult,
    const float* __restrict__ mats,
    const float* __restrict__ Wp, const float* __restrict__ bp,
    const float* __restrict__ ln_g, const float* __restrict__ ln_b,
    const float* __restrict__ muW1, const float* __restrict__ mub1,
    const float* __restrict__ muW2, const float* __restrict__ mub2,
    const float* __restrict__ muW3, const float* __restrict__ mub3,
    const float* __restrict__ siW1, const float* __restrict__ sib1,
    const float* __restrict__ siW2, const float* __restrict__ sib2,
    const float* __restrict__ siW3, const float* __restrict__ sib3,
    float* __restrict__ out) {
  const int b = blockIdx.x;
  const int tid = threadIdx.x;
  const int lane = tid & 63;
  const int wv = tid >> 6;

  __shared__ float part[256];
  __shared__ float mbuf[64];
  __shared__ float ctx_lds[192];
  __shared__ __align__(16) float h1_lds[256];
  __shared__ float psum[4];
  __shared__ float msum[4];
  __shared__ uint32_t kA[NSTEPS];
  __shared__ uint32_t kB[NSTEPS];

  // ---- per-step keys: jax.random.split(key(1), 2520) ----
  for (int i = tid; i < NSTEPS; i += 256) {
#if PARTITIONABLE
    uint32_t o0, o1;
    tf2x32(0u, 1u, 0u, (uint32_t)i, o0, o1);   // fold-like split: both outputs
    kA[i] = o0; kB[i] = o1;
#else
    uint32_t o0, o1, d0, d1;
    if (i < 1260) {
      tf2x32(0u, 1u, (uint32_t)(2 * i),     (uint32_t)(2 * i + 2520),     o0, d0);
      tf2x32(0u, 1u, (uint32_t)(2 * i + 1), (uint32_t)(2 * i + 1 + 2520), o1, d1);
    } else {
      tf2x32(0u, 1u, (uint32_t)(2 * i - 2520),     (uint32_t)(2 * i),     d0, o0);
      tf2x32(0u, 1u, (uint32_t)(2 * i + 1 - 2520), (uint32_t)(2 * i + 1), d1, o1);
    }
    kA[i] = o0; kB[i] = o1;
#endif
  }

  // ---- context aggregator: H = LN(tanh(X@Wp+bp)); ctx = [mean_t, std_t(ddof=1), last] ----
  float h[64];
  {
    float x0 = X[(b * NT + tid) * 2 + 0];
    float x1 = X[(b * NT + tid) * 2 + 1];
    float s = 0.f;
#pragma unroll
    for (int c = 0; c < 64; ++c) {
      float pre = __builtin_fmaf(x1, Wp[64 + c], x0 * Wp[c]) + bp[c];
      h[c] = eigen_tanh(pre);
      s += h[c];
    }
    float m = s * 0.015625f;
    float vs = 0.f;
#pragma unroll
    for (int c = 0; c < 64; ++c) { float d = h[c] - m; vs = __builtin_fmaf(d, d, vs); }
    float den = sqrtf(vs * 0.015625f + 1e-5f);
#pragma unroll
    for (int c = 0; c < 64; ++c)
      h[c] = ((h[c] - m) / den) * ln_g[c] + ln_b[c];
  }
  // channel means over T (rows live in registers; butterfly within wave, 4 partials)
#pragma unroll
  for (int c = 0; c < 64; ++c) {
    float v = h[c];
    v += __shfl_xor(v, 32, 64); v += __shfl_xor(v, 16, 64);
    v += __shfl_xor(v, 8, 64);  v += __shfl_xor(v, 4, 64);
    v += __shfl_xor(v, 2, 64);  v += __shfl_xor(v, 1, 64);
    if (lane == 0) part[wv * 64 + c] = v;
  }
  __syncthreads();
  if (tid < 64) {
    float m = ((part[tid] + part[64 + tid]) + (part[128 + tid] + part[192 + tid])) * (1.0f / 256.0f);
    mbuf[tid] = m;
    ctx_lds[tid] = m;
  }
  __syncthreads();
#pragma unroll
  for (int c = 0; c < 64; ++c) {
    float d = h[c] - mbuf[c];
    float v = d * d;
    v += __shfl_xor(v, 32, 64); v += __shfl_xor(v, 16, 64);
    v += __shfl_xor(v, 8, 64);  v += __shfl_xor(v, 4, 64);
    v += __shfl_xor(v, 2, 64);  v += __shfl_xor(v, 1, 64);
    if (lane == 0) part[wv * 64 + c] = v;
  }
  if (tid == 255) {
#pragma unroll
    for (int c = 0; c < 64; ++c) ctx_lds[128 + c] = h[c];  // H[:, -1, :]
  }
  __syncthreads();
  if (tid < 64) {
    float vs = (part[tid] + part[64 + tid]) + (part[128 + tid] + part[192 + tid]);
    ctx_lds[64 + tid] = sqrtf(vs / 255.0f);  // ddof=1
  }
  __syncthreads();

  // ---- per-thread MLP constants: thread 0..127 -> mu output j, 128..255 -> si output j ----
  const bool is_mu = tid < 128;
  const int j = is_mu ? tid : tid - 128;
  const float* W1 = is_mu ? muW1 : siW1;
  const float* W2 = is_mu ? muW2 : siW2;
  float c1 = (is_mu ? mub1 : sib1)[j];  // fold bias + constant ctx part of layer 1
  for (int c = 0; c < 192; ++c)
    c1 = __builtin_fmaf(ctx_lds[c], W1[(2 + c) * 128 + j], c1);
  const float w10 = W1[j];         // W1 row 0 (r_mean)
  const float w11 = W1[128 + j];   // W1 row 1 (t)
  const float b2s = (is_mu ? mub2 : sib2)[j];
  const float w3s = (is_mu ? muW3 : siW3)[j];
  const float b3mu = mub3[0];
  const float b3si = sib3[0];

  // W2 column j pinned in registers: eight named 512-bit vectors (no alloca,
  // promote-alloca can't demote these to scratch).
  f16v w2v0, w2v1, w2v2, w2v3, w2v4, w2v5, w2v6, w2v7;
#define LOADW2(V, SEG) \
  _Pragma("unroll") \
  for (int k = 0; k < 16; ++k) V[k] = W2[((SEG) * 16 + k) * 128 + j];
  LOADW2(w2v0, 0) LOADW2(w2v1, 1) LOADW2(w2v2, 2) LOADW2(w2v3, 3)
  LOADW2(w2v4, 4) LOADW2(w2v5, 5) LOADW2(w2v6, 6) LOADW2(w2v7, 7)
#undef LOADW2

  // ---- path state: thread q owns path q of batch b ----
  float r = r_ult[b];
  float area = 0.f;
  const uint32_t cnt = (uint32_t)(b * NQ + tid);  // linear index into (B,Q)

  const float DTF = (float)(1.0 / 252.0);
  const float SQDT = 0.06299407883487120442f;  // f32(sqrt(1/252))
  const float TSTEP = 1.0f / 2519.0f;          // linspace(0,1,2520) step

#pragma unroll 1
  for (int s = 0; s < NSTEPS; ++s) {
    // r.mean over 256 paths
    float v = r;
    v += __shfl_xor(v, 32, 64); v += __shfl_xor(v, 16, 64);
    v += __shfl_xor(v, 8, 64);  v += __shfl_xor(v, 4, 64);
    v += __shfl_xor(v, 2, 64);  v += __shfl_xor(v, 1, 64);
    if (lane == 0) psum[wv] = v;
    __syncthreads();  // barrier 1
    const float r_mean = ((psum[0] + psum[1]) + (psum[2] + psum[3])) * (1.0f / 256.0f);
    const float tval = TSTEP * (float)s;

    // dW: independent of MLP chain — scheduled to overlap
    uint32_t q0, q1;
#if PARTITIONABLE
    tf2x32(kA[s], kB[s], 0u, cnt, q0, q1);
    const uint32_t bits = q0 ^ q1;
#else
    const uint32_t c0 = (cnt < 8192u) ? cnt : (cnt - 8192u);
    tf2x32(kA[s], kB[s], c0, c0 + 8192u, q0, q1);
    const uint32_t bits = (cnt < 8192u) ? q0 : q1;
#endif
    const float dW = bits_to_normal(bits) * SQDT;

    // layer 1 (ctx part precomputed): 2 FMAs + gelu
    float pre = __builtin_fmaf(tval, w11, __builtin_fmaf(r_mean, w10, c1));
    h1_lds[tid] = gelu_exact(pre);
    __syncthreads();  // barrier 2

    // layer 2: 128-MAC dot; h1 via LDS float4 broadcasts, W2 column in registers.
    // Accumulation order identical to round-1 kernel (4 mod-4 chains, then
    // ((a0+a1)+(a2+a3))) — keeps the output bit-exact vs the reference.
    const float* hb = h1_lds + (is_mu ? 0 : 128);
    f4v acc = (f4v){0.f, 0.f, 0.f, 0.f};
#define SEG4(V, SEG) \
    { \
      f4v h4a = *(const f4v*)(hb + (SEG) * 16 + 0); \
      f4v w4a = __builtin_shufflevector(V, V, 0, 1, 2, 3); \
      acc = __builtin_elementwise_fma(h4a, w4a, acc); \
      f4v h4b = *(const f4v*)(hb + (SEG) * 16 + 4); \
      f4v w4b = __builtin_shufflevector(V, V, 4, 5, 6, 7); \
      acc = __builtin_elementwise_fma(h4b, w4b, acc); \
      f4v h4c = *(const f4v*)(hb + (SEG) * 16 + 8); \
      f4v w4c = __builtin_shufflevector(V, V, 8, 9, 10, 11); \
      acc = __builtin_elementwise_fma(h4c, w4c, acc); \
      f4v h4d = *(const f4v*)(hb + (SEG) * 16 + 12); \
      f4v w4d = __builtin_shufflevector(V, V, 12, 13, 14, 15); \
      acc = __builtin_elementwise_fma(h4d, w4d, acc); \
    }
    SEG4(w2v0, 0) SEG4(w2v1, 1) SEG4(w2v2, 2) SEG4(w2v3, 3)
    SEG4(w2v4, 4) SEG4(w2v5, 5) SEG4(w2v6, 6) SEG4(w2v7, 7)
#undef SEG4
    float h2 = ((acc[0] + acc[1]) + (acc[2] + acc[3])) + b2s;

    // layer 3: dot over 128 outputs = 2-wave reduction
    float p = gelu_exact(h2) * w3s;
    p += __shfl_xor(p, 32, 64); p += __shfl_xor(p, 16, 64);
    p += __shfl_xor(p, 8, 64);  p += __shfl_xor(p, 4, 64);
    p += __shfl_xor(p, 2, 64);  p += __shfl_xor(p, 1, 64);
    if (lane == 0) msum[wv] = p;
    __syncthreads();  // barrier 3
    const float mu = (msum[0] + msum[1]) + b3mu;
    const float si_raw = (msum[2] + msum[3]) + b3si;
    const float si = softplus_jax(si_raw) + 1e-5f;

    // r = (r + mu*DT) + si*dW ; area += r*DT — non-fused to mirror XLA elementwise
    r = __fadd_rn(__fadd_rn(r, __fmul_rn(mu, DTF)), __fmul_rn(si, dW));
    area = __fadd_rn(area, __fmul_rn(r, DTF));
  }

  // area.mean(1) then output: (am * (m/maxT)) / m for each maturity
  float v2 = area;
  v2 += __shfl_xor(v2, 32, 64); v2 += __shfl_xor(v2, 16, 64);
  v2 += __shfl_xor(v2, 8, 64);  v2 += __shfl_xor(v2, 4, 64);
  v2 += __shfl_xor(v2, 2, 64);  v2 += __shfl_xor(v2, 1, 64);
  if (lane == 0) psum[wv] = v2;
  __syncthreads();
  if (tid < NMAT) {
    const float am = ((psum[0] + psum[1]) + (psum[2] + psum[3])) * (1.0f / 256.0f);
    float mx = mats[0];
#pragma unroll
    for (int i = 1; i < NMAT; ++i) mx = fmaxf(mx, mats[i]);
    const float m = mats[tid];
    const float frac = m / (mx + 1e-12f);
    out[b * NMAT + tid] = (am * frac) / (m + 1e-12f);
  }
}

extern "C" void kernel_launch(void* const* d_in, const int* in_sizes, int n_in,
                              void* d_out, int out_size, void* d_ws, size_t ws_size,
                              hipStream_t stream) {
  (void)in_sizes; (void)n_in; (void)d_ws; (void)ws_size; (void)out_size;
  const float* X      = (const float*)d_in[0];
  const float* r_ult  = (const float*)d_in[1];
  const float* mats   = (const float*)d_in[2];
  const float* Wp     = (const float*)d_in[3];
  const float* bp     = (const float*)d_in[4];
  const float* ln_g   = (const float*)d_in[5];
  const float* ln_b   = (const float*)d_in[6];
  const float* muW1   = (const float*)d_in[7];
  const float* mub1   = (const float*)d_in[8];
  const float* muW2   = (const float*)d_in[9];
  const float* mub2   = (const float*)d_in[10];
  const float* muW3   = (const float*)d_in[11];
  const float* mub3   = (const float*)d_in[12];
  const float* siW1   = (const float*)d_in[13];
  const float* sib1   = (const float*)d_in[14];
  const float* siW2   = (const float*)d_in[15];
  const float* sib2   = (const float*)d_in[16];
  const float* siW3   = (const float*)d_in[17];
  const float* sib3   = (const float*)d_in[18];
  hipLaunchKernelGGL(ModeloNeuralVasicek_88158498717914_kernel,
                     dim3(NB), dim3(256), 0, stream,
                     X, r_ult, mats, Wp, bp, ln_g, ln_b,
                     muW1, mub1, muW2, mub2, muW3, mub3,
                     siW1, sib1, siW2, sib2, siW3, sib3,
                     (float*)d_out);
}